// Round 9
// baseline (3953.257 us; speedup 1.0000x reference)
//
#include <hip/hip_runtime.h>

typedef _Float16 f16;
typedef _Float16 f16x8 __attribute__((ext_vector_type(8)));
typedef _Float16 f16x4 __attribute__((ext_vector_type(4)));
typedef float    f32x4 __attribute__((ext_vector_type(4)));

#define HN 1024
#define G4 4096
#define MATEL (4096ull*1024ull)
#define TT 512
#define RB 16

// ---- workspace layout (bytes) ----
#define OFF_W0   (0ull)                    // [2][4096][1024] f16 : enc/dec Whh0
#define OFF_WI1  (16ull<<20)               // [2][4096][1024] f16 : enc/dec Wih1
#define OFF_WH1  (32ull<<20)               // [2][4096][1024] f16 : enc/dec Whh1
#define OFF_B0   (48ull<<20)               // [2][4096] f32 fused bias layer0
#define OFF_B1   (OFF_B0 + 32768ull)       // [2][4096] f32 fused bias layer1
#define OFF_WX   (OFF_B0 + 65536ull)       // [2][4096] f32 Wih0 column
#define OFF_WFC  (OFF_B0 + 98304ull)       // [1024] f32 fc_w
#define OFF_FCB  (OFF_B0 + 102400ull)      // [1] f32 fc_b
#define OFF_F0   (OFF_B0 + 131072ull)      // u32[64*2*64]  L0 per-wave stamps (256B-strided)
#define OFF_F1   (OFF_F0 + 32768ull)       // u32[128*64]   L1 stamps (256B-strided)
#define OFF_TFM  (OFF_F1 + 32768ull)       // uchar[256] normalized tf_mask
#define OFF_RING (49ull<<20)

#define LDS_W   131072                     // 64 rows x 2048B swizzled weights
#define LDS_EX  16384                      // f16 exchange [8 tiles][16][16][4kq]
#define LDS_TOT (LDS_W + LDS_EX + 2048)    // + xbuf[32] + red[256]

// ---- communication helpers ----
// producers: no-return atomic RMW -> executed at IC; per-WAVE s_waitcnt vmcnt(0) then
//            stamp own sub-slot BEFORE the block barrier (consumers don't need the barrier).
// consumers (DEEP): plain cached vector loads (fresh addresses -> no stale-L2 hazard;
//                   replay-stale lines hold bit-identical values by determinism).
// stamps: one slot per producing wave, 256B stride (own line, spread across IC slices).
__device__ __forceinline__ void st8(f16* p, unsigned long long q) {
  (void)__hip_atomic_exchange((unsigned long long*)p, q, __ATOMIC_RELAXED, __HIP_MEMORY_SCOPE_AGENT);
}
__device__ __forceinline__ void st4f(float* p, float v) {
  union { float f; unsigned int u; } c; c.f = v;
  (void)__hip_atomic_exchange((unsigned int*)p, c.u, __ATOMIC_RELAXED, __HIP_MEMORY_SCOPE_AGENT);
}
__device__ __forceinline__ void stampA(unsigned int* slot, unsigned int v) {
  (void)__hip_atomic_exchange(slot, v, __ATOMIC_RELAXED, __HIP_MEMORY_SCOPE_AGENT);
}
template<bool DEEP>
__device__ __forceinline__ f16x8 ldA(const f16* p) {
  if constexpr (DEEP) {
    return *(const f16x8*)p;
  } else {
    union { unsigned long long q[2]; f16x8 v; } u;
    const unsigned long long* pq = (const unsigned long long*)p;
    u.q[0] = __hip_atomic_load(pq,     __ATOMIC_RELAXED, __HIP_MEMORY_SCOPE_AGENT);
    u.q[1] = __hip_atomic_load(pq + 1, __ATOMIC_RELAXED, __HIP_MEMORY_SCOPE_AGENT);
    return u.v;
  }
}
template<bool DEEP>
__device__ __forceinline__ float ldP(const float* p) {
  if constexpr (DEEP) return *p;
  else return __hip_atomic_load(p, __ATOMIC_RELAXED, __HIP_MEMORY_SCOPE_AGENT);
}
// wave-local wait: poll CNT stamp slots [base, base+CNT); no __syncthreads -> the wave
// proceeds the moment its K-quarter's producers are done.
template<int CNT, int SLP>
__device__ __forceinline__ void wavewait(const unsigned int* f, int base, unsigned int tgt,
                                         long long& budget) {
  const unsigned int* p = f + (size_t)(base + ((int)(threadIdx.x & 63) & (CNT - 1))) * 64;
  for (;;) {
    unsigned int v = __hip_atomic_load(p, __ATOMIC_RELAXED, __HIP_MEMORY_SCOPE_AGENT);
    if (__all((int)(v >= tgt))) break;
    __builtin_amdgcn_s_sleep(SLP);
    if (--budget < 0) break;               // anti-hang: degrade, never deadlock
  }
  asm volatile("" ::: "memory");
}
// block-wide wait on f1 (NS=128 slots, stride 64 u32), wave-0 polls then barrier releases.
template<int NS, int SLP>
__device__ __forceinline__ void wgwaitA(const unsigned int* f, unsigned int tgt, long long& budget) {
  if (threadIdx.x < 64) {
    const int i0 = (int)threadIdx.x * 64;
    for (;;) {
      unsigned int v = __hip_atomic_load(f + i0, __ATOMIC_RELAXED, __HIP_MEMORY_SCOPE_AGENT);
      if (NS == 128) {
        unsigned int v2 = __hip_atomic_load(f + 4096 + i0, __ATOMIC_RELAXED, __HIP_MEMORY_SCOPE_AGENT);
        v = v < v2 ? v : v2;
      }
      if (__all((int)(v >= tgt))) break;
      __builtin_amdgcn_s_sleep(SLP);
      if (--budget < 0) break;             // anti-hang: degrade, never deadlock
    }
  }
  __syncthreads();
  asm volatile("" ::: "memory");
}
// block-wide wait on f0 (64 WGs x 2 per-wave sub-slots) -- !DEEP fallback only.
template<int SLP>
__device__ __forceinline__ void wgwaitF0(const unsigned int* f, unsigned int tgt, long long& budget) {
  if (threadIdx.x < 64) {
    const int i0 = (int)threadIdx.x * 128;
    for (;;) {
      unsigned int v  = __hip_atomic_load(f + i0,      __ATOMIC_RELAXED, __HIP_MEMORY_SCOPE_AGENT);
      unsigned int v2 = __hip_atomic_load(f + i0 + 64, __ATOMIC_RELAXED, __HIP_MEMORY_SCOPE_AGENT);
      v = v < v2 ? v : v2;
      if (__all((int)(v >= tgt))) break;
      __builtin_amdgcn_s_sleep(SLP);
      if (--budget < 0) break;
    }
  }
  __syncthreads();
  asm volatile("" ::: "memory");
}

__device__ __forceinline__ float sigmoidf_(float x) { return 1.f / (1.f + __expf(-x)); }
__device__ __forceinline__ float tanhf_(float x) {
  x = fminf(15.f, fmaxf(-15.f, x));
  float e = __expf(2.f * x);
  return (e - 1.f) / (e + 1.f);
}
__device__ __forceinline__ float sum4h(const f16* p) {
  f16x4 v = *(const f16x4*)p;
  return (float)v[0] + (float)v[1] + (float)v[2] + (float)v[3];
}

// ---------- prep: fp32 -> fp16 weight conversion ----------
__global__ void prep_mats(const float* __restrict__ s0, const float* __restrict__ s1,
                          const float* __restrict__ s2, const float* __restrict__ s3,
                          const float* __restrict__ s4, const float* __restrict__ s5,
                          char* __restrict__ ws)
{
  const int m = blockIdx.y;
  const float* S = (m==0)?s0:(m==1)?s1:(m==2)?s2:(m==3)?s3:(m==4)?s4:s5;
  f16* D;
  if (m < 2)      D = (f16*)(ws + OFF_W0)  + (size_t)m     * MATEL;
  else if (m < 4) D = (f16*)(ws + OFF_WI1) + (size_t)(m-2) * MATEL;
  else            D = (f16*)(ws + OFF_WH1) + (size_t)(m-4) * MATEL;
  const size_t nq = MATEL / 4;
  for (size_t i = (size_t)blockIdx.x * blockDim.x + threadIdx.x; i < nq;
       i += (size_t)gridDim.x * blockDim.x) {
    const float4 v = ((const float4*)S)[i];
    f16x4 h; h[0] = (f16)v.x; h[1] = (f16)v.y; h[2] = (f16)v.z; h[3] = (f16)v.w;
    ((f16x4*)D)[i] = h;
  }
}

__global__ void prep_small(const float* eb0a, const float* eb0b,
                           const float* db0a, const float* db0b,
                           const float* eb1a, const float* eb1b,
                           const float* db1a, const float* db1b,
                           const float* ewx, const float* dwx,
                           const float* fw,  const float* fb,
                           char* __restrict__ ws)
{
  float* B0v  = (float*)(ws + OFF_B0);
  float* B1v  = (float*)(ws + OFF_B1);
  float* WXv  = (float*)(ws + OFF_WX);
  float* WFCv = (float*)(ws + OFF_WFC);
  float* FCBv = (float*)(ws + OFF_FCB);
  int i = blockIdx.x * 256 + threadIdx.x;
  if (i < 4096) {
    B0v[i]        = eb0a[i] + eb0b[i];
    B0v[4096 + i] = db0a[i] + db0b[i];
    B1v[i]        = eb1a[i] + eb1b[i];
    B1v[4096 + i] = db1a[i] + db1b[i];
    WXv[i]        = ewx[i];
    WXv[4096 + i] = dwx[i];
  }
  if (i < 1024) WFCv[i] = fw[i];
  if (i == 0)   FCBv[0] = fb[0];
}

// ---------- prep: sniff tf_mask encoding (int32 / float32 / uint8) and normalize ----------
__global__ void prep_tfm(const unsigned char* __restrict__ raw, char* __restrict__ ws)
{
  __shared__ int flg[2];
  unsigned char* dst = (unsigned char*)(ws + OFF_TFM);
  const int i = threadIdx.x;             // one block, 256 threads
  if (i == 0) { flg[0] = 1; flg[1] = 1; }
  __syncthreads();
  const unsigned char b = raw[i];
  const int r = i & 3;
  const bool oki = (r == 0) ? (b <= 1) : (b == 0);
  const bool okf = (r == 3) ? (b == 0 || b == 0x3f)
                 : (r == 2) ? (b == 0 || b == 0x80)
                 : (b == 0);
  if (!oki) atomicAnd(&flg[0], 0);
  if (!okf) atomicAnd(&flg[1], 0);
  __syncthreads();
  if (flg[0])      dst[i] = (((const int*)(const void*)raw)[i] != 0);
  else if (flg[1]) dst[i] = (((const float*)(const void*)raw)[i] != 0.f);
  else             dst[i] = (b != 0);
}

// ---------- persistent dataflow kernel ----------
// roles: wg 0..63 = layer0 (16 cells each), wg 64..191 = layer1 (8 cells each), wg 192 = pred writer.
// MFMA 16x16x32 f16: A lane = h[row=l&15][k=(l>>4)*8+j]; B lane = W[col=l&15][k=(l>>4)*8+j];
// D lane = [row=(l>>4)*4+r][col=l&15].
// exch LDS layout: elem = (tile*256 + row16*16 + col')*4 + kq, col' = (col+row16)&15.
// f0: 2 sub-slots per L0 WG (one per elementwise wave), stamped pre-barrier after the
// wave's own vmcnt drain. f1: 1 slot per L1 WG (wave-0 writes all h1+part), same scheme.
// quarter kq's producers: f0 slots [kq*32,(kq+1)*32), f1 slots [kq*32,(kq+1)*32).
template<bool DEEP>
__global__ __launch_bounds__(256, 1)
void seq2seq_main(const float* __restrict__ prev,
                  const float* __restrict__ nfut,
                  char* __restrict__ ws,
                  f16* __restrict__ h0r,
                  f16* __restrict__ h1r,
                  float* __restrict__ part,
                  float* __restrict__ out)
{
  extern __shared__ char lds[];
  f16*   exch = (f16*)(lds + LDS_W);
  float* xbuf = (float*)(lds + LDS_W + LDS_EX);
  float* red  = xbuf + 32;

  const int tid  = threadIdx.x;
  const int wid  = tid >> 6;
  const int lane = tid & 63;
  const int l15  = lane & 15;
  const int lgrp = lane >> 4;
  const int kq   = wid;               // K-quarter per wave
  const int wg   = blockIdx.x;

  const f16* W0  = (const f16*)(ws + OFF_W0);
  const f16* WI1 = (const f16*)(ws + OFF_WI1);
  const f16* WH1 = (const f16*)(ws + OFF_WH1);
  const float* B0v  = (const float*)(ws + OFF_B0);
  const float* B1v  = (const float*)(ws + OFF_B1);
  const float* WXv  = (const float*)(ws + OFF_WX);
  const float* WFCv = (const float*)(ws + OFF_WFC);
  const float* FCBv = (const float*)(ws + OFF_FCB);
  const unsigned char* tfm = (const unsigned char*)(ws + OFF_TFM);
  unsigned int* f0 = (unsigned int*)(ws + OFF_F0);
  unsigned int* f1 = (unsigned int*)(ws + OFF_F1);

  long long budget = 1ll << 23;

  if (wg < 64) {
    // ================= layer 0 =================
    const int cell0 = wg * 16;
    const int erow = tid & 31, ecq = (tid >> 5) & 3;   // elementwise: 4 cells per thread
    float cst[4] = {0.f, 0.f, 0.f, 0.f};
    float bias[4][4], wxv[4][4];
    for (int T = 0; T < TT; ++T) {
      const int phase = T >> 8;
      if ((T & 255) == 0) {
        __syncthreads();
        const f16* Wm = W0 + (size_t)phase * MATEL;
        { int R = tid >> 2, q = tid & 3;
          int g = R >> 4, rr = R & 15;
          const f16* srow = Wm + (size_t)(g * HN + cell0 + rr) * HN;
          char* drow = lds + R * 2048;
          int sw = (R & 7) << 4;
          #pragma unroll
          for (int i = 0; i < 32; ++i) {
            int ch = q * 32 + i;
            f16x8 v = *(const f16x8*)(srow + ch * 8);
            *(f16x8*)(drow + ((ch * 16) ^ sw)) = v;
          }
        }
        if (tid < 128) {
          #pragma unroll
          for (int g = 0; g < 4; ++g)
            #pragma unroll
            for (int j = 0; j < 4; ++j) {
              bias[g][j] = B0v[phase * G4 + g * HN + cell0 + ecq * 4 + j];
              wxv[g][j]  = WXv[phase * G4 + g * HN + cell0 + ecq * 4 + j];
            }
        }
        __syncthreads();
      }
      if constexpr (!DEEP) {
        if (T > 0)   wgwaitF0<1>(f0, (unsigned)T, budget);
        if (T >= RB) wgwaitA<128, 1>(f1, (unsigned)(T - RB + 1), budget);   // ring safety
      }

      f32x4 acc[4][2];
      #pragma unroll
      for (int g = 0; g < 4; ++g) { acc[g][0] = (f32x4){0,0,0,0}; acc[g][1] = (f32x4){0,0,0,0}; }
      if (T > 0) {
        if constexpr (DEEP) wavewait<32, 1>(f0, kq * 32, (unsigned)T, budget);
        const size_t slotR = DEEP ? (size_t)(T - 1) : (size_t)((T - 1) & 15);
        const f16* hb = h0r + slotR * (32 * HN);
        f16x8 a[2][8];
        #pragma unroll
        for (int m = 0; m < 2; ++m)
          #pragma unroll
          for (int ks = 0; ks < 8; ++ks)
            a[m][ks] = ldA<DEEP>(hb + (m * 16 + l15) * HN + kq * 256 + ks * 32 + lgrp * 8);
        #pragma unroll
        for (int ks = 0; ks < 8; ++ks) {
          const int kel = kq * 256 + ks * 32 + lgrp * 8;
          #pragma unroll
          for (int g = 0; g < 4; ++g) {
            const int R = g * 16 + l15;
            f16x8 b = *(const f16x8*)(lds + ((R * 2048 + kel * 2) ^ ((R & 7) << 4)));
            acc[g][0] = __builtin_amdgcn_mfma_f32_16x16x32_f16(a[0][ks], b, acc[g][0], 0, 0, 0);
            acc[g][1] = __builtin_amdgcn_mfma_f32_16x16x32_f16(a[1][ks], b, acc[g][1], 0, 0, 0);
          }
        }
      }
      // exch write with (col+row)&15 swizzle
      #pragma unroll
      for (int g = 0; g < 4; ++g)
        #pragma unroll
        for (int m = 0; m < 2; ++m)
          #pragma unroll
          for (int r = 0; r < 4; ++r) {
            const int row16 = lgrp * 4 + r;
            const int colp  = (l15 + row16) & 15;
            exch[((g * 2 + m) * 256 + row16 * 16 + colp) * 4 + kq] = (f16)acc[g][m][r];
          }

      // x input (after GEMM so decoder feedback wait overlaps the big GEMM)
      const int s = T - 256;
      const bool needp = (T >= 257) && (tfm[s - 1] == 0);
      if (needp) {
        wgwaitA<128, 1>(f1, (unsigned)T, budget);
        { const int b = tid & 31, seg = tid >> 5;      // 256 threads: 16 loads each
          const float* pp = part + (size_t)(s - 1) * 4096;
          float sum = 0.f;
          #pragma unroll 8
          for (int k = 0; k < 16; ++k) sum += ldP<DEEP>(pp + (seg * 16 + k) * 32 + b);
          red[tid] = sum;
        }
      } else if (T < 256) {
        if (tid < 32) xbuf[tid] = prev[tid * 256 + T];
      } else if (s == 0) {
        if (tid < 32) xbuf[tid] = 0.f;
      } else {
        if (tid < 32) xbuf[tid] = nfut[tid * 256 + (s - 1)];
      }
      __syncthreads();
      if (needp) {
        if (tid < 32) {
          float sum = FCBv[0];
          #pragma unroll
          for (int j = 0; j < 8; ++j) sum += red[j * 32 + tid];
          xbuf[tid] = sum;
        }
        __syncthreads();
      }
      // elementwise: thread owns (row, 4 consecutive cells) -> one 8B IC-resident store
      if (tid < 128) {
        const int m = erow >> 4, row16 = erow & 15;
        const float xb = xbuf[erow];
        const size_t slotW = DEEP ? (size_t)T : (size_t)(T & 15);
        f16* h0w = h0r + slotW * (32 * HN);
        union { f16 h[4]; unsigned long long q; } pk;
        #pragma unroll
        for (int j = 0; j < 4; ++j) {
          const int colp = (ecq * 4 + j + row16) & 15;
          float gv[4];
          #pragma unroll
          for (int g = 0; g < 4; ++g)
            gv[g] = sum4h(exch + ((g * 2 + m) * 256 + row16 * 16 + colp) * 4)
                  + bias[g][j] + xb * wxv[g][j];
          const float iv = sigmoidf_(gv[0]), fv = sigmoidf_(gv[1]);
          const float gg = tanhf_(gv[2]),    ov = sigmoidf_(gv[3]);
          cst[j] = fv * cst[j] + iv * gg;
          pk.h[j] = (f16)(ov * tanhf_(cst[j]));
        }
        st8(h0w + erow * HN + cell0 + ecq * 4, pk.q);
      }
      // pre-barrier per-wave stamp: drain OWN wave's stores, signal immediately
      if (wid < 2) {
        asm volatile("s_waitcnt vmcnt(0)" ::: "memory");
        if (lane == 0) stampA(f0 + (size_t)(wg * 2 + wid) * 64, (unsigned)(T + 1));
      }
      __syncthreads();                  // exch(T) reads vs exch(T+1) writes separation
    }
  } else if (wg < 192) {
    // ================= layer 1 =================
    const int w1 = wg - 64;
    const int cell0 = w1 * 8;
    const int erow = tid & 31, ehf = (tid >> 5) & 1;   // 4 cells per thread, 64 threads
    float cst[4] = {0.f, 0.f, 0.f, 0.f};
    float bias[4][4], fcw[4];
    for (int T = 0; T < TT; ++T) {
      const int phase = T >> 8;
      if ((T & 255) == 0) {
        __syncthreads();
        { int R = tid >> 2, q = tid & 3;
          int mat = R >> 5, r5 = R & 31;
          int tl = (r5 >> 4) & 1, hf = (r5 >> 3) & 1;
          int grow = (tl * 2 + hf) * HN + cell0 + (r5 & 7);
          const f16* Wm = (mat ? WH1 : WI1) + (size_t)phase * MATEL;
          const f16* srow = Wm + (size_t)grow * HN;
          char* drow = lds + R * 2048;
          int sw = (R & 7) << 4;
          #pragma unroll
          for (int i = 0; i < 32; ++i) {
            int ch = q * 32 + i;
            f16x8 v = *(const f16x8*)(srow + ch * 8);
            *(f16x8*)(drow + ((ch * 16) ^ sw)) = v;
          }
        }
        if (tid < 64) {
          #pragma unroll
          for (int g = 0; g < 4; ++g)
            #pragma unroll
            for (int j = 0; j < 4; ++j)
              bias[g][j] = B1v[phase * G4 + g * HN + cell0 + ehf * 4 + j];
          #pragma unroll
          for (int j = 0; j < 4; ++j) fcw[j] = WFCv[cell0 + ehf * 4 + j];
        }
        __syncthreads();
      }
      if constexpr (!DEEP) {
        if (T > 0) wgwaitA<128, 1>(f1, (unsigned)T, budget);
      }

      // GEMM-A (prep): Whh1 x h1(T-1) -- off the h0 critical path
      f32x4 acc[2][2];
      acc[0][0] = acc[0][1] = acc[1][0] = acc[1][1] = (f32x4){0, 0, 0, 0};
      f16x8 a[2][8];
      if (T > 0) {
        if constexpr (DEEP) wavewait<32, 1>(f1, kq * 32, (unsigned)T, budget);
        const size_t slotR = DEEP ? (size_t)(T - 1) : (size_t)((T - 1) & 15);
        const f16* hb = h1r + slotR * (32 * HN);
        #pragma unroll
        for (int m = 0; m < 2; ++m)
          #pragma unroll
          for (int ks = 0; ks < 8; ++ks)
            a[m][ks] = ldA<DEEP>(hb + (m * 16 + l15) * HN + kq * 256 + ks * 32 + lgrp * 8);
        #pragma unroll
        for (int ks = 0; ks < 8; ++ks) {
          const int kel = kq * 256 + ks * 32 + lgrp * 8;
          #pragma unroll
          for (int t = 0; t < 2; ++t) {
            const int R = 32 + t * 16 + l15;
            f16x8 b = *(const f16x8*)(lds + ((R * 2048 + kel * 2) ^ ((R & 7) << 4)));
            acc[t][0] = __builtin_amdgcn_mfma_f32_16x16x32_f16(a[0][ks], b, acc[t][0], 0, 0, 0);
            acc[t][1] = __builtin_amdgcn_mfma_f32_16x16x32_f16(a[1][ks], b, acc[t][1], 0, 0, 0);
          }
        }
      }
      // GEMM-B (critical): Wih1 x h0(T)
      if constexpr (DEEP) wavewait<32, 1>(f0, kq * 32, (unsigned)(T + 1), budget);
      else                wgwaitF0<1>(f0, (unsigned)(T + 1), budget);
      { const size_t slotR = DEEP ? (size_t)T : (size_t)(T & 15);
        const f16* hb = h0r + slotR * (32 * HN);
        #pragma unroll
        for (int m = 0; m < 2; ++m)
          #pragma unroll
          for (int ks = 0; ks < 8; ++ks)
            a[m][ks] = ldA<DEEP>(hb + (m * 16 + l15) * HN + kq * 256 + ks * 32 + lgrp * 8);
      }
      #pragma unroll
      for (int ks = 0; ks < 8; ++ks) {
        const int kel = kq * 256 + ks * 32 + lgrp * 8;
        #pragma unroll
        for (int t = 0; t < 2; ++t) {
          const int R = t * 16 + l15;
          f16x8 b = *(const f16x8*)(lds + ((R * 2048 + kel * 2) ^ ((R & 7) << 4)));
          acc[t][0] = __builtin_amdgcn_mfma_f32_16x16x32_f16(a[0][ks], b, acc[t][0], 0, 0, 0);
          acc[t][1] = __builtin_amdgcn_mfma_f32_16x16x32_f16(a[1][ks], b, acc[t][1], 0, 0, 0);
        }
      }
      #pragma unroll
      for (int t = 0; t < 2; ++t)
        #pragma unroll
        for (int m = 0; m < 2; ++m)
          #pragma unroll
          for (int r = 0; r < 4; ++r) {
            const int row16 = lgrp * 4 + r;
            const int colp  = (l15 + row16) & 15;
            exch[((t * 2 + m) * 256 + row16 * 16 + colp) * 4 + kq] = (f16)acc[t][m][r];
          }
      __syncthreads();
      // elementwise: gate g of cell c lives in tile (g>>1), col (g&1)*8 + c (c = local 0..7)
      float pv = 0.f;
      if (tid < 64) {
        const int m = erow >> 4, row16 = erow & 15;
        const size_t slotW = DEEP ? (size_t)T : (size_t)(T & 15);
        f16* h1w = h1r + slotW * (32 * HN);
        union { f16 h[4]; unsigned long long q; } pk;
        #pragma unroll
        for (int j = 0; j < 4; ++j) {
          const int c = ehf * 4 + j;
          float gv[4];
          #pragma unroll
          for (int g = 0; g < 4; ++g) {
            const int colp = (((g & 1) * 8 + c) + row16) & 15;
            gv[g] = sum4h(exch + (((g >> 1) * 2 + m) * 256 + row16 * 16 + colp) * 4) + bias[g][j];
          }
          cst[j] = sigmoidf_(gv[1]) * cst[j] + sigmoidf_(gv[0]) * tanhf_(gv[2]);
          const float hv = sigmoidf_(gv[3]) * tanhf_(cst[j]);
          pk.h[j] = (f16)hv;
          pv += fcw[j] * hv;
        }
        st8(h1w + erow * HN + cell0 + ehf * 4, pk.q);
        if (T >= 256) {
          pv += __shfl_xor(pv, 32);      // combine the two cell-halves of this row
          if (ehf == 0)
            st4f(part + (size_t)(T - 256) * 4096 + w1 * 32 + erow, pv);
        }
      }
      // pre-barrier stamp: wave 0 wrote ALL h1 + part -> drain its stores, signal now
      if (wid == 0) {
        asm volatile("s_waitcnt vmcnt(0)" ::: "memory");
        if (lane == 0) stampA(f1 + (size_t)w1 * 64, (unsigned)(T + 1));
      }
      __syncthreads();                  // exch(T) reads vs exch(T+1) writes separation
    }
  } else if (wg == 192) {
    // ================= pred writer (off critical path: coarse sleep poll) =================
    for (int sD = 0; sD < 256; ++sD) {
      wgwaitA<128, 16>(f1, (unsigned)(257 + sD), budget);
      { const int b = tid & 31, seg = tid >> 5;        // 256 threads: 16 loads each
        const float* pp = part + (size_t)sD * 4096;
        float sum = 0.f;
        #pragma unroll 8
        for (int k = 0; k < 16; ++k) sum += ldP<DEEP>(pp + (seg * 16 + k) * 32 + b);
        red[tid] = sum;
      }
      __syncthreads();
      if (tid < 32) {
        float sum = FCBv[0];
        #pragma unroll
        for (int j = 0; j < 8; ++j) sum += red[j * 32 + tid];
        out[tid * 256 + sD] = sum;
      }
      __syncthreads();
    }
  }
}

extern "C" void kernel_launch(void* const* d_in, const int* in_sizes, int n_in,
                              void* d_out, int out_size, void* d_ws, size_t ws_size,
                              hipStream_t stream)
{
  (void)in_sizes; (void)n_in; (void)out_size;
  char* ws = (char*)d_ws;

  // adaptive ring layout: deep (no address reuse -> cached consumer loads) if ws allows
  const bool deep = ws_size >= (118ull << 20);
  const size_t ringsz = deep ? (32ull << 20) : (1ull << 20);       // per h ring
  const size_t offH0 = OFF_RING;
  const size_t offH1 = offH0 + ringsz;
  const size_t offPart = offH1 + ringsz;
  if (!deep && ws_size < (offPart + (4ull << 20))) return;          // too small: fail visibly

  // zero stamp arrays every launch (rings/partials are written-before-read by construction)
  hipMemsetAsync(ws + OFF_F0, 0, 65536, stream);

  // fp16 weight conversion: {enc,dec}Whh0, {enc,dec}Wih1, {enc,dec}Whh1
  prep_mats<<<dim3(1024, 6), 256, 0, stream>>>(
      (const float*)d_in[4],  (const float*)d_in[12],
      (const float*)d_in[7],  (const float*)d_in[15],
      (const float*)d_in[8],  (const float*)d_in[16], ws);

  prep_small<<<16, 256, 0, stream>>>(
      (const float*)d_in[5],  (const float*)d_in[6],    // enc bih0/bhh0
      (const float*)d_in[13], (const float*)d_in[14],   // dec bih0/bhh0
      (const float*)d_in[9],  (const float*)d_in[10],   // enc bih1/bhh1
      (const float*)d_in[17], (const float*)d_in[18],   // dec bih1/bhh1
      (const float*)d_in[3],  (const float*)d_in[11],   // enc/dec Wih0 column
      (const float*)d_in[19], (const float*)d_in[20],   // fc_w, fc_b
      ws);

  // normalize tf_mask (sniffs int32 / float32 / uint8 encodings)
  prep_tfm<<<1, 256, 0, stream>>>((const unsigned char*)d_in[2], ws);

  f16* h0r = (f16*)(ws + offH0);
  f16* h1r = (f16*)(ws + offH1);
  float* part = (float*)(ws + offPart);

  if (deep) {
    auto fn = seq2seq_main<true>;
    hipFuncSetAttribute((const void*)fn, hipFuncAttributeMaxDynamicSharedMemorySize, LDS_TOT);
    fn<<<dim3(193), dim3(256), LDS_TOT, stream>>>(
        (const float*)d_in[0], (const float*)d_in[1], ws, h0r, h1r, part, (float*)d_out);
  } else {
    auto fn = seq2seq_main<false>;
    hipFuncSetAttribute((const void*)fn, hipFuncAttributeMaxDynamicSharedMemorySize, LDS_TOT);
    fn<<<dim3(193), dim3(256), LDS_TOT, stream>>>(
        (const float*)d_in[0], (const float*)d_in[1], ws, h0r, h1r, part, (float*)d_out);
  }
}

// Round 10
// 3773.896 us; speedup vs baseline: 1.0475x; 1.0475x over previous
//
#include <hip/hip_runtime.h>

typedef _Float16 f16;
typedef _Float16 f16x8 __attribute__((ext_vector_type(8)));
typedef _Float16 f16x4 __attribute__((ext_vector_type(4)));
typedef float    f32x4 __attribute__((ext_vector_type(4)));

#define HN 1024
#define G4 4096
#define MATEL (4096ull*1024ull)
#define TT 512
#define RB 16

// ---- workspace layout (bytes) ----
#define OFF_W0   (0ull)                    // [2][4096][1024] f16 : enc/dec Whh0
#define OFF_WI1  (16ull<<20)               // [2][4096][1024] f16 : enc/dec Wih1
#define OFF_WH1  (32ull<<20)               // [2][4096][1024] f16 : enc/dec Whh1
#define OFF_B0   (48ull<<20)               // [2][4096] f32 fused bias layer0
#define OFF_B1   (OFF_B0 + 32768ull)       // [2][4096] f32 fused bias layer1
#define OFF_WX   (OFF_B0 + 65536ull)       // [2][4096] f32 Wih0 column
#define OFF_WFC  (OFF_B0 + 98304ull)       // [1024] f32 fc_w
#define OFF_FCB  (OFF_B0 + 102400ull)      // [1] f32 fc_b
#define OFF_F0   (OFF_B0 + 131072ull)      // u32[64*64]  L0 stamps, 256B-strided (64 lines)
#define OFF_F1   (OFF_F0 + 16384ull)       // u32[128*64] L1 stamps, 256B-strided (128 lines)
#define OFF_TFM  (OFF_F1 + 32768ull)       // uchar[256] normalized tf_mask
#define OFF_RING (49ull<<20)

#define LDS_W   131072                     // 64 rows x 2048B swizzled weights
#define LDS_EX  16384                      // f16 exchange [8 tiles][16][16][4kq]
#define LDS_TOT (LDS_W + LDS_EX + 1024)    // + xbuf[32] + red[128]

// ---- communication helpers ----
// producers: no-return atomic RMW -> executed at IC, agent-visible after vmcnt drain.
// consumers (DEEP): plain cached vector loads (fresh addresses -> no stale-L2 hazard;
//                   replay-stale lines hold bit-identical values by determinism).
// stamps: per-WG slot at 256B stride (each its own line, spread across IC slices).
__device__ __forceinline__ void st8(f16* p, unsigned long long q) {
  (void)__hip_atomic_exchange((unsigned long long*)p, q, __ATOMIC_RELAXED, __HIP_MEMORY_SCOPE_AGENT);
}
__device__ __forceinline__ void st4f(float* p, float v) {
  union { float f; unsigned int u; } c; c.f = v;
  (void)__hip_atomic_exchange((unsigned int*)p, c.u, __ATOMIC_RELAXED, __HIP_MEMORY_SCOPE_AGENT);
}
__device__ __forceinline__ void stampA(unsigned int* slot, unsigned int v) {
  (void)__hip_atomic_exchange(slot, v, __ATOMIC_RELAXED, __HIP_MEMORY_SCOPE_AGENT);
}
template<bool DEEP>
__device__ __forceinline__ f16x8 ldA(const f16* p) {
  if constexpr (DEEP) {
    return *(const f16x8*)p;
  } else {
    union { unsigned long long q[2]; f16x8 v; } u;
    const unsigned long long* pq = (const unsigned long long*)p;
    u.q[0] = __hip_atomic_load(pq,     __ATOMIC_RELAXED, __HIP_MEMORY_SCOPE_AGENT);
    u.q[1] = __hip_atomic_load(pq + 1, __ATOMIC_RELAXED, __HIP_MEMORY_SCOPE_AGENT);
    return u.v;
  }
}
template<bool DEEP>
__device__ __forceinline__ float ldP(const float* p) {
  if constexpr (DEEP) return *p;
  else return __hip_atomic_load(p, __ATOMIC_RELAXED, __HIP_MEMORY_SCOPE_AGENT);
}
// wave-local wait: poll the CNT stamp slots [base, base+CNT) that produce THIS wave's
// K-quarter; no __syncthreads -> the wave proceeds the moment its quarter is ready.
template<int CNT, int SLP>
__device__ __forceinline__ void wavewait(const unsigned int* f, int base, unsigned int tgt,
                                         long long& budget) {
  const unsigned int* p = f + (size_t)(base + ((int)(threadIdx.x & 63) & (CNT - 1))) * 64;
  for (;;) {
    unsigned int v = __hip_atomic_load(p, __ATOMIC_RELAXED, __HIP_MEMORY_SCOPE_AGENT);
    if (__all((int)(v >= tgt))) break;
    __builtin_amdgcn_s_sleep(SLP);
    if (--budget < 0) break;               // anti-hang: degrade, never deadlock
  }
  asm volatile("" ::: "memory");
}
// block-wide wait (full producer set), wave-0 polls then barrier releases the WG.
template<int NS, int SLP>
__device__ __forceinline__ void wgwaitA(const unsigned int* f, unsigned int tgt, long long& budget) {
  if (threadIdx.x < 64) {
    const int i0 = (int)threadIdx.x * 64;          // 256B-strided slots
    for (;;) {
      unsigned int v = __hip_atomic_load(f + i0, __ATOMIC_RELAXED, __HIP_MEMORY_SCOPE_AGENT);
      if (NS == 128) {
        unsigned int v2 = __hip_atomic_load(f + 4096 + i0, __ATOMIC_RELAXED, __HIP_MEMORY_SCOPE_AGENT);
        v = v < v2 ? v : v2;
      }
      if (__all((int)(v >= tgt))) break;
      __builtin_amdgcn_s_sleep(SLP);
      if (--budget < 0) break;             // anti-hang: degrade, never deadlock
    }
  }
  __syncthreads();
  asm volatile("" ::: "memory");           // no load hoisting above the wait
}

__device__ __forceinline__ float sigmoidf_(float x) { return 1.f / (1.f + __expf(-x)); }
__device__ __forceinline__ float tanhf_(float x) {
  x = fminf(15.f, fmaxf(-15.f, x));
  float e = __expf(2.f * x);
  return (e - 1.f) / (e + 1.f);
}
__device__ __forceinline__ float sum4h(const f16* p) {
  f16x4 v = *(const f16x4*)p;
  return (float)v[0] + (float)v[1] + (float)v[2] + (float)v[3];
}

// ---------- prep: fp32 -> fp16 weight conversion ----------
__global__ void prep_mats(const float* __restrict__ s0, const float* __restrict__ s1,
                          const float* __restrict__ s2, const float* __restrict__ s3,
                          const float* __restrict__ s4, const float* __restrict__ s5,
                          char* __restrict__ ws)
{
  const int m = blockIdx.y;
  const float* S = (m==0)?s0:(m==1)?s1:(m==2)?s2:(m==3)?s3:(m==4)?s4:s5;
  f16* D;
  if (m < 2)      D = (f16*)(ws + OFF_W0)  + (size_t)m     * MATEL;
  else if (m < 4) D = (f16*)(ws + OFF_WI1) + (size_t)(m-2) * MATEL;
  else            D = (f16*)(ws + OFF_WH1) + (size_t)(m-4) * MATEL;
  const size_t nq = MATEL / 4;
  for (size_t i = (size_t)blockIdx.x * blockDim.x + threadIdx.x; i < nq;
       i += (size_t)gridDim.x * blockDim.x) {
    const float4 v = ((const float4*)S)[i];
    f16x4 h; h[0] = (f16)v.x; h[1] = (f16)v.y; h[2] = (f16)v.z; h[3] = (f16)v.w;
    ((f16x4*)D)[i] = h;
  }
}

__global__ void prep_small(const float* eb0a, const float* eb0b,
                           const float* db0a, const float* db0b,
                           const float* eb1a, const float* eb1b,
                           const float* db1a, const float* db1b,
                           const float* ewx, const float* dwx,
                           const float* fw,  const float* fb,
                           char* __restrict__ ws)
{
  float* B0v  = (float*)(ws + OFF_B0);
  float* B1v  = (float*)(ws + OFF_B1);
  float* WXv  = (float*)(ws + OFF_WX);
  float* WFCv = (float*)(ws + OFF_WFC);
  float* FCBv = (float*)(ws + OFF_FCB);
  int i = blockIdx.x * 256 + threadIdx.x;
  if (i < 4096) {
    B0v[i]        = eb0a[i] + eb0b[i];
    B0v[4096 + i] = db0a[i] + db0b[i];
    B1v[i]        = eb1a[i] + eb1b[i];
    B1v[4096 + i] = db1a[i] + db1b[i];
    WXv[i]        = ewx[i];
    WXv[4096 + i] = dwx[i];
  }
  if (i < 1024) WFCv[i] = fw[i];
  if (i == 0)   FCBv[0] = fb[0];
}

// ---------- prep: sniff tf_mask encoding (int32 / float32 / uint8) and normalize ----------
__global__ void prep_tfm(const unsigned char* __restrict__ raw, char* __restrict__ ws)
{
  __shared__ int flg[2];
  unsigned char* dst = (unsigned char*)(ws + OFF_TFM);
  const int i = threadIdx.x;             // one block, 256 threads
  if (i == 0) { flg[0] = 1; flg[1] = 1; }
  __syncthreads();
  const unsigned char b = raw[i];
  const int r = i & 3;
  const bool oki = (r == 0) ? (b <= 1) : (b == 0);
  const bool okf = (r == 3) ? (b == 0 || b == 0x3f)
                 : (r == 2) ? (b == 0 || b == 0x80)
                 : (b == 0);
  if (!oki) atomicAnd(&flg[0], 0);
  if (!okf) atomicAnd(&flg[1], 0);
  __syncthreads();
  if (flg[0])      dst[i] = (((const int*)(const void*)raw)[i] != 0);
  else if (flg[1]) dst[i] = (((const float*)(const void*)raw)[i] != 0.f);
  else             dst[i] = (b != 0);
}

// ---------- persistent dataflow kernel ----------
// roles: wg 0..63 = layer0 (16 cells each), wg 64..191 = layer1 (8 cells each), wg 192 = pred writer.
// MFMA 16x16x32 f16: A lane = h[row=l&15][k=(l>>4)*8+j]; B lane = W[col=l&15][k=(l>>4)*8+j];
// D lane = [row=(l>>4)*4+r][col=l&15].
// exch LDS layout: elem = (tile*256 + row16*16 + col')*4 + kq, col' = (col+row16)&15.
// fine-grained waits: wave kq's K-quarter [kq*256,(kq+1)*256) is produced by
//   L0 WGs [kq*16,(kq+1)*16)  (h0) / L1 WGs [kq*32,(kq+1)*32) (h1).
template<bool DEEP>
__global__ __launch_bounds__(256, 1)
void seq2seq_main(const float* __restrict__ prev,
                  const float* __restrict__ nfut,
                  char* __restrict__ ws,
                  f16* __restrict__ h0r,
                  f16* __restrict__ h1r,
                  float* __restrict__ part,
                  float* __restrict__ out)
{
  extern __shared__ char lds[];
  f16*   exch = (f16*)(lds + LDS_W);
  float* xbuf = (float*)(lds + LDS_W + LDS_EX);
  float* red  = xbuf + 32;

  const int tid  = threadIdx.x;
  const int wid  = tid >> 6;
  const int lane = tid & 63;
  const int l15  = lane & 15;
  const int lgrp = lane >> 4;
  const int kq   = wid;               // K-quarter per wave
  const int wg   = blockIdx.x;

  const f16* W0  = (const f16*)(ws + OFF_W0);
  const f16* WI1 = (const f16*)(ws + OFF_WI1);
  const f16* WH1 = (const f16*)(ws + OFF_WH1);
  const float* B0v  = (const float*)(ws + OFF_B0);
  const float* B1v  = (const float*)(ws + OFF_B1);
  const float* WXv  = (const float*)(ws + OFF_WX);
  const float* WFCv = (const float*)(ws + OFF_WFC);
  const float* FCBv = (const float*)(ws + OFF_FCB);
  const unsigned char* tfm = (const unsigned char*)(ws + OFF_TFM);
  unsigned int* f0 = (unsigned int*)(ws + OFF_F0);
  unsigned int* f1 = (unsigned int*)(ws + OFF_F1);

  long long budget = 1ll << 23;

  if (wg < 64) {
    // ================= layer 0 =================
    const int cell0 = wg * 16;
    const int erow = tid & 31, ecq = (tid >> 5) & 3;   // elementwise: 4 cells per thread
    float cst[4] = {0.f, 0.f, 0.f, 0.f};
    float bias[4][4], wxv[4][4];
    for (int T = 0; T < TT; ++T) {
      const int phase = T >> 8;
      if ((T & 255) == 0) {
        __syncthreads();
        const f16* Wm = W0 + (size_t)phase * MATEL;
        { int R = tid >> 2, q = tid & 3;
          int g = R >> 4, rr = R & 15;
          const f16* srow = Wm + (size_t)(g * HN + cell0 + rr) * HN;
          char* drow = lds + R * 2048;
          int sw = (R & 7) << 4;
          #pragma unroll
          for (int i = 0; i < 32; ++i) {
            int ch = q * 32 + i;
            f16x8 v = *(const f16x8*)(srow + ch * 8);
            *(f16x8*)(drow + ((ch * 16) ^ sw)) = v;
          }
        }
        if (tid < 128) {
          #pragma unroll
          for (int g = 0; g < 4; ++g)
            #pragma unroll
            for (int j = 0; j < 4; ++j) {
              bias[g][j] = B0v[phase * G4 + g * HN + cell0 + ecq * 4 + j];
              wxv[g][j]  = WXv[phase * G4 + g * HN + cell0 + ecq * 4 + j];
            }
        }
        __syncthreads();
      }
      if constexpr (!DEEP) {
        if (T > 0)   wgwaitA<64, 1>(f0, (unsigned)T, budget);
        if (T >= RB) wgwaitA<128, 1>(f1, (unsigned)(T - RB + 1), budget);   // ring safety
      }

      f32x4 acc[4][2];
      #pragma unroll
      for (int g = 0; g < 4; ++g) { acc[g][0] = (f32x4){0,0,0,0}; acc[g][1] = (f32x4){0,0,0,0}; }
      if (T > 0) {
        if constexpr (DEEP) wavewait<16, 1>(f0, kq * 16, (unsigned)T, budget);
        const size_t slotR = DEEP ? (size_t)(T - 1) : (size_t)((T - 1) & 15);
        const f16* hb = h0r + slotR * (32 * HN);
        f16x8 a[2][8];
        #pragma unroll
        for (int m = 0; m < 2; ++m)
          #pragma unroll
          for (int ks = 0; ks < 8; ++ks)
            a[m][ks] = ldA<DEEP>(hb + (m * 16 + l15) * HN + kq * 256 + ks * 32 + lgrp * 8);
        #pragma unroll
        for (int ks = 0; ks < 8; ++ks) {
          const int kel = kq * 256 + ks * 32 + lgrp * 8;
          #pragma unroll
          for (int g = 0; g < 4; ++g) {
            const int R = g * 16 + l15;
            f16x8 b = *(const f16x8*)(lds + ((R * 2048 + kel * 2) ^ ((R & 7) << 4)));
            acc[g][0] = __builtin_amdgcn_mfma_f32_16x16x32_f16(a[0][ks], b, acc[g][0], 0, 0, 0);
            acc[g][1] = __builtin_amdgcn_mfma_f32_16x16x32_f16(a[1][ks], b, acc[g][1], 0, 0, 0);
          }
        }
      }
      // exch write with (col+row)&15 swizzle
      #pragma unroll
      for (int g = 0; g < 4; ++g)
        #pragma unroll
        for (int m = 0; m < 2; ++m)
          #pragma unroll
          for (int r = 0; r < 4; ++r) {
            const int row16 = lgrp * 4 + r;
            const int colp  = (l15 + row16) & 15;
            exch[((g * 2 + m) * 256 + row16 * 16 + colp) * 4 + kq] = (f16)acc[g][m][r];
          }

      // x input (after GEMM so decoder feedback wait overlaps the big GEMM)
      const int s = T - 256;
      const bool needp = (T >= 257) && (tfm[s - 1] == 0);
      if (needp) {
        wgwaitA<128, 1>(f1, (unsigned)T, budget);
        if (tid < 128) {
          const int b = tid & 31, seg = tid >> 5;
          const float* pp = part + (size_t)(s - 1) * 4096;
          float sum = 0.f;
          #pragma unroll 8
          for (int k = 0; k < 32; ++k) sum += ldP<DEEP>(pp + (seg * 32 + k) * 32 + b);
          red[tid] = sum;
        }
      } else if (T < 256) {
        if (tid < 32) xbuf[tid] = prev[tid * 256 + T];
      } else if (s == 0) {
        if (tid < 32) xbuf[tid] = 0.f;
      } else {
        if (tid < 32) xbuf[tid] = nfut[tid * 256 + (s - 1)];
      }
      __syncthreads();
      if (needp) {
        if (tid < 32) xbuf[tid] = red[tid] + red[32 + tid] + red[64 + tid] + red[96 + tid] + FCBv[0];
        __syncthreads();
      }
      // elementwise: thread owns (row, 4 consecutive cells) -> one 8B IC-resident store
      if (tid < 128) {
        const int m = erow >> 4, row16 = erow & 15;
        const float xb = xbuf[erow];
        const size_t slotW = DEEP ? (size_t)T : (size_t)(T & 15);
        f16* h0w = h0r + slotW * (32 * HN);
        union { f16 h[4]; unsigned long long q; } pk;
        #pragma unroll
        for (int j = 0; j < 4; ++j) {
          const int colp = (ecq * 4 + j + row16) & 15;
          float gv[4];
          #pragma unroll
          for (int g = 0; g < 4; ++g)
            gv[g] = sum4h(exch + ((g * 2 + m) * 256 + row16 * 16 + colp) * 4)
                  + bias[g][j] + xb * wxv[g][j];
          const float iv = sigmoidf_(gv[0]), fv = sigmoidf_(gv[1]);
          const float gg = tanhf_(gv[2]),    ov = sigmoidf_(gv[3]);
          cst[j] = fv * cst[j] + iv * gg;
          pk.h[j] = (f16)(ov * tanhf_(cst[j]));
        }
        st8(h0w + erow * HN + cell0 + ecq * 4, pk.q);
      }
      __syncthreads();                  // drains vmcnt: swaps executed at IC
      if (tid == 0) stampA(f0 + wg * 64, (unsigned)(T + 1));
    }
  } else if (wg < 192) {
    // ================= layer 1 =================
    const int w1 = wg - 64;
    const int cell0 = w1 * 8;
    const int erow = tid & 31, ehf = (tid >> 5) & 1;   // 4 cells per thread, 64 threads
    float cst[4] = {0.f, 0.f, 0.f, 0.f};
    float bias[4][4], fcw[4];
    for (int T = 0; T < TT; ++T) {
      const int phase = T >> 8;
      if ((T & 255) == 0) {
        __syncthreads();
        { int R = tid >> 2, q = tid & 3;
          int mat = R >> 5, r5 = R & 31;
          int tl = (r5 >> 4) & 1, hf = (r5 >> 3) & 1;
          int grow = (tl * 2 + hf) * HN + cell0 + (r5 & 7);
          const f16* Wm = (mat ? WH1 : WI1) + (size_t)phase * MATEL;
          const f16* srow = Wm + (size_t)grow * HN;
          char* drow = lds + R * 2048;
          int sw = (R & 7) << 4;
          #pragma unroll
          for (int i = 0; i < 32; ++i) {
            int ch = q * 32 + i;
            f16x8 v = *(const f16x8*)(srow + ch * 8);
            *(f16x8*)(drow + ((ch * 16) ^ sw)) = v;
          }
        }
        if (tid < 64) {
          #pragma unroll
          for (int g = 0; g < 4; ++g)
            #pragma unroll
            for (int j = 0; j < 4; ++j)
              bias[g][j] = B1v[phase * G4 + g * HN + cell0 + ehf * 4 + j];
          #pragma unroll
          for (int j = 0; j < 4; ++j) fcw[j] = WFCv[cell0 + ehf * 4 + j];
        }
        __syncthreads();
      }
      if constexpr (!DEEP) {
        if (T > 0) wgwaitA<128, 1>(f1, (unsigned)T, budget);
      }

      // GEMM-A (prep): Whh1 x h1(T-1) -- off the h0 critical path
      f32x4 acc[2][2];
      acc[0][0] = acc[0][1] = acc[1][0] = acc[1][1] = (f32x4){0, 0, 0, 0};
      f16x8 a[2][8];
      if (T > 0) {
        if constexpr (DEEP) wavewait<32, 1>(f1, kq * 32, (unsigned)T, budget);
        const size_t slotR = DEEP ? (size_t)(T - 1) : (size_t)((T - 1) & 15);
        const f16* hb = h1r + slotR * (32 * HN);
        #pragma unroll
        for (int m = 0; m < 2; ++m)
          #pragma unroll
          for (int ks = 0; ks < 8; ++ks)
            a[m][ks] = ldA<DEEP>(hb + (m * 16 + l15) * HN + kq * 256 + ks * 32 + lgrp * 8);
        #pragma unroll
        for (int ks = 0; ks < 8; ++ks) {
          const int kel = kq * 256 + ks * 32 + lgrp * 8;
          #pragma unroll
          for (int t = 0; t < 2; ++t) {
            const int R = 32 + t * 16 + l15;
            f16x8 b = *(const f16x8*)(lds + ((R * 2048 + kel * 2) ^ ((R & 7) << 4)));
            acc[t][0] = __builtin_amdgcn_mfma_f32_16x16x32_f16(a[0][ks], b, acc[t][0], 0, 0, 0);
            acc[t][1] = __builtin_amdgcn_mfma_f32_16x16x32_f16(a[1][ks], b, acc[t][1], 0, 0, 0);
          }
        }
      }
      // GEMM-B (critical): Wih1 x h0(T)
      if constexpr (DEEP) wavewait<16, 1>(f0, kq * 16, (unsigned)(T + 1), budget);
      else                wgwaitA<64, 1>(f0, (unsigned)(T + 1), budget);
      { const size_t slotR = DEEP ? (size_t)T : (size_t)(T & 15);
        const f16* hb = h0r + slotR * (32 * HN);
        #pragma unroll
        for (int m = 0; m < 2; ++m)
          #pragma unroll
          for (int ks = 0; ks < 8; ++ks)
            a[m][ks] = ldA<DEEP>(hb + (m * 16 + l15) * HN + kq * 256 + ks * 32 + lgrp * 8);
      }
      #pragma unroll
      for (int ks = 0; ks < 8; ++ks) {
        const int kel = kq * 256 + ks * 32 + lgrp * 8;
        #pragma unroll
        for (int t = 0; t < 2; ++t) {
          const int R = t * 16 + l15;
          f16x8 b = *(const f16x8*)(lds + ((R * 2048 + kel * 2) ^ ((R & 7) << 4)));
          acc[t][0] = __builtin_amdgcn_mfma_f32_16x16x32_f16(a[0][ks], b, acc[t][0], 0, 0, 0);
          acc[t][1] = __builtin_amdgcn_mfma_f32_16x16x32_f16(a[1][ks], b, acc[t][1], 0, 0, 0);
        }
      }
      #pragma unroll
      for (int t = 0; t < 2; ++t)
        #pragma unroll
        for (int m = 0; m < 2; ++m)
          #pragma unroll
          for (int r = 0; r < 4; ++r) {
            const int row16 = lgrp * 4 + r;
            const int colp  = (l15 + row16) & 15;
            exch[((t * 2 + m) * 256 + row16 * 16 + colp) * 4 + kq] = (f16)acc[t][m][r];
          }
      __syncthreads();
      // elementwise: gate g of cell c lives in tile (g>>1), col (g&1)*8 + c (c = local 0..7)
      float pv = 0.f;
      if (tid < 64) {
        const int m = erow >> 4, row16 = erow & 15;
        const size_t slotW = DEEP ? (size_t)T : (size_t)(T & 15);
        f16* h1w = h1r + slotW * (32 * HN);
        union { f16 h[4]; unsigned long long q; } pk;
        #pragma unroll
        for (int j = 0; j < 4; ++j) {
          const int c = ehf * 4 + j;
          float gv[4];
          #pragma unroll
          for (int g = 0; g < 4; ++g) {
            const int colp = (((g & 1) * 8 + c) + row16) & 15;
            gv[g] = sum4h(exch + (((g >> 1) * 2 + m) * 256 + row16 * 16 + colp) * 4) + bias[g][j];
          }
          cst[j] = sigmoidf_(gv[1]) * cst[j] + sigmoidf_(gv[0]) * tanhf_(gv[2]);
          const float hv = sigmoidf_(gv[3]) * tanhf_(cst[j]);
          pk.h[j] = (f16)hv;
          pv += fcw[j] * hv;
        }
        st8(h1w + erow * HN + cell0 + ehf * 4, pk.q);
        if (T >= 256) {
          pv += __shfl_xor(pv, 32);      // combine the two cell-halves of this row
          if (ehf == 0)
            st4f(part + (size_t)(T - 256) * 4096 + w1 * 32 + erow, pv);
        }
      }
      __syncthreads();                  // drains vmcnt: swaps executed at IC
      if (tid == 0) stampA(f1 + w1 * 64, (unsigned)(T + 1));
    }
  } else if (wg == 192) {
    // ================= pred writer (off critical path: coarse sleep poll) =================
    for (int sD = 0; sD < 256; ++sD) {
      wgwaitA<128, 16>(f1, (unsigned)(257 + sD), budget);
      if (tid < 128) {
        const int b = tid & 31, seg = tid >> 5;
        const float* pp = part + (size_t)sD * 4096;
        float sum = 0.f;
        #pragma unroll 8
        for (int k = 0; k < 32; ++k) sum += ldP<DEEP>(pp + (seg * 32 + k) * 32 + b);
        red[tid] = sum;
      }
      __syncthreads();
      if (tid < 32) out[tid * 256 + sD] = red[tid] + red[32 + tid] + red[64 + tid] + red[96 + tid] + FCBv[0];
      __syncthreads();
    }
  }
}

extern "C" void kernel_launch(void* const* d_in, const int* in_sizes, int n_in,
                              void* d_out, int out_size, void* d_ws, size_t ws_size,
                              hipStream_t stream)
{
  (void)in_sizes; (void)n_in; (void)out_size;
  char* ws = (char*)d_ws;

  // adaptive ring layout: deep (no address reuse -> cached consumer loads) if ws allows
  const bool deep = ws_size >= (118ull << 20);
  const size_t ringsz = deep ? (32ull << 20) : (1ull << 20);       // per h ring
  const size_t offH0 = OFF_RING;
  const size_t offH1 = offH0 + ringsz;
  const size_t offPart = offH1 + ringsz;
  if (!deep && ws_size < (offPart + (4ull << 20))) return;          // too small: fail visibly

  // zero stamp arrays every launch (rings/partials are written-before-read by construction)
  hipMemsetAsync(ws + OFF_F0, 0, 49152, stream);

  // fp16 weight conversion: {enc,dec}Whh0, {enc,dec}Wih1, {enc,dec}Whh1
  prep_mats<<<dim3(1024, 6), 256, 0, stream>>>(
      (const float*)d_in[4],  (const float*)d_in[12],
      (const float*)d_in[7],  (const float*)d_in[15],
      (const float*)d_in[8],  (const float*)d_in[16], ws);

  prep_small<<<16, 256, 0, stream>>>(
      (const float*)d_in[5],  (const float*)d_in[6],    // enc bih0/bhh0
      (const float*)d_in[13], (const float*)d_in[14],   // dec bih0/bhh0
      (const float*)d_in[9],  (const float*)d_in[10],   // enc bih1/bhh1
      (const float*)d_in[17], (const float*)d_in[18],   // dec bih1/bhh1
      (const float*)d_in[3],  (const float*)d_in[11],   // enc/dec Wih0 column
      (const float*)d_in[19], (const float*)d_in[20],   // fc_w, fc_b
      ws);

  // normalize tf_mask (sniffs int32 / float32 / uint8 encodings)
  prep_tfm<<<1, 256, 0, stream>>>((const unsigned char*)d_in[2], ws);

  f16* h0r = (f16*)(ws + offH0);
  f16* h1r = (f16*)(ws + offH1);
  float* part = (float*)(ws + offPart);

  if (deep) {
    auto fn = seq2seq_main<true>;
    hipFuncSetAttribute((const void*)fn, hipFuncAttributeMaxDynamicSharedMemorySize, LDS_TOT);
    fn<<<dim3(193), dim3(256), LDS_TOT, stream>>>(
        (const float*)d_in[0], (const float*)d_in[1], ws, h0r, h1r, part, (float*)d_out);
  } else {
    auto fn = seq2seq_main<false>;
    hipFuncSetAttribute((const void*)fn, hipFuncAttributeMaxDynamicSharedMemorySize, LDS_TOT);
    fn<<<dim3(193), dim3(256), LDS_TOT, stream>>>(
        (const float*)d_in[0], (const float*)d_in[1], ws, h0r, h1r, part, (float*)d_out);
  }
}